// Round 7
// baseline (1972.426 us; speedup 1.0000x reference)
//
#include <hip/hip_runtime.h>

#define NB    8
#define NPTS  8192
#define NCTR  1024
#define KNN   64
#define NGRP  8192
#define SAMP  524288
#define EPSB  1e-5f

// ---- ws layout (bytes), total SMALL = ~31.5 MB, BIG = ~166 MB ----
#define OFF_CIDX 0ull
#define OFF_NIDX 32768ull
#define OFF_SS   2129920ull
#define OFF_PSUM 2134016ull
#define OFF_PSQR 4231168ull
#define OFF_GMAX 6328320ull
#define OFF_GMIN 14716928ull
#define OFF_FT   23105536ull
#define OFF_Y1   31494144ull
#define NEED_BIG 165711872ull

typedef unsigned short ushort8 __attribute__((ext_vector_type(8)));
typedef short short8v __attribute__((ext_vector_type(8)));
typedef float f32x4 __attribute__((ext_vector_type(4)));
typedef float f32x2 __attribute__((ext_vector_type(2)));

__device__ __forceinline__ unsigned short f2b(float f) {
  unsigned int u = __builtin_bit_cast(unsigned int, f);
  u += 0x7fffu + ((u >> 16) & 1u);
  return (unsigned short)(u >> 16);
}
__device__ __forceinline__ float b2f(unsigned short s) {
  unsigned int u = ((unsigned int)s) << 16;
  return __builtin_bit_cast(float, u);
}

// DPP max steps: r = max(r, dpp_move(r)); bound_ctrl=1 -> invalid src reads 0
// (identity for non-negative f32 dist and for unsigned keys).
template <int CTRL>
__device__ __forceinline__ float dppmax(float x) {
  int m = __builtin_amdgcn_update_dpp(0, __builtin_bit_cast(int, x), CTRL, 0xf, 0xf, true);
  return fmaxf(x, __builtin_bit_cast(float, m));
}
template <int CTRL>
__device__ __forceinline__ unsigned dppumax(unsigned x) {
  unsigned m = (unsigned)__builtin_amdgcn_update_dpp(0, (int)x, CTRL, 0xf, 0xf, true);
  return (x > m) ? x : m;
}

// ---------------- FPS: cell-sorted points, per-thread bbox pruning ----------------
// Points counting-sorted by 8x8x8 cell into LDS float4 (orig idx bit-cast in .w).
// Thread owns 32 sorted (spatially local) points in registers + bbox + cached
// packed best (distbits<<32)|key, key = ((8191-orig)<<13|slot)+1 so u64/u32 max
// == (max dist, then min orig idx) == numpy first-occurrence argmax. Skip the
// 32-point update when d2min(bbox,center)*0.9999 >= my max dist (exact: then
// every point's f32 d2 >= its dst, min is a no-op; margin >> 5-ulp bound).
__global__ __launch_bounds__(256) void fps_kernel(const float* __restrict__ coords,
                                                  int* __restrict__ cidx,
                                                  float* __restrict__ centers_out) {
  const int b = blockIdx.x, t = threadIdx.x;
  const int wid = t >> 6, lane = t & 63;
  __shared__ float4 pts[NPTS];                 // 128 KB sorted (x,y,z,origidx)
  __shared__ int cnt[512];
  __shared__ int part[256];
  __shared__ int cstart[512];
  __shared__ unsigned long long red[2][4];
  const float* cb = coords + (size_t)b * 3 * NPTS;

  // ---- counting sort by cell ----
  cnt[t] = 0; cnt[t + 256] = 0;
  __syncthreads();
  for (int i = t; i < NPTS; i += 256) {
    float x = cb[i], y = cb[NPTS + i], z = cb[2 * NPTS + i];
    int ix = min(max((int)(x * 8.f), 0), 7);
    int iy = min(max((int)(y * 8.f), 0), 7);
    int iz = min(max((int)(z * 8.f), 0), 7);
    atomicAdd(&cnt[ix + 8 * iy + 64 * iz], 1);
  }
  __syncthreads();
  part[t] = cnt[2 * t] + cnt[2 * t + 1];
  __syncthreads();
  for (int off = 1; off < 256; off <<= 1) {
    int v = (t >= off) ? part[t - off] : 0;
    __syncthreads();
    part[t] += v;
    __syncthreads();
  }
  {
    int e = (t > 0) ? part[t - 1] : 0;
    cstart[2 * t] = e;
    cstart[2 * t + 1] = e + cnt[2 * t];
  }
  __syncthreads();
  cnt[t] = 0; cnt[t + 256] = 0;
  __syncthreads();
  for (int i = t; i < NPTS; i += 256) {
    float x = cb[i], y = cb[NPTS + i], z = cb[2 * NPTS + i];
    int ix = min(max((int)(x * 8.f), 0), 7);
    int iy = min(max((int)(y * 8.f), 0), 7);
    int iz = min(max((int)(z * 8.f), 0), 7);
    int c = ix + 8 * iy + 64 * iz;
    int r = atomicAdd(&cnt[c], 1);
    int slot = cstart[c] + r;
    pts[slot] = make_float4(x, y, z, __builtin_bit_cast(float, i));
  }
  __syncthreads();

  // ---- per-thread register load: 32 sorted points + bbox + keys ----
  constexpr int PT = 32, P2 = 16;
  f32x2 px[P2], py[P2], pz[P2], dst[P2];
  unsigned noi[PT];
  float lox = 1e30f, loy = 1e30f, loz = 1e30f;
  float hix = -1e30f, hiy = -1e30f, hiz = -1e30f;
#pragma unroll
  for (int j = 0; j < P2; ++j) {
    int s0 = t * PT + 2 * j;
    float4 p0 = pts[s0];
    float4 p1 = pts[s0 + 1];
    px[j] = (f32x2){p0.x, p1.x};
    py[j] = (f32x2){p0.y, p1.y};
    pz[j] = (f32x2){p0.z, p1.z};
    dst[j] = (f32x2){1e10f, 1e10f};
    lox = fminf(lox, fminf(p0.x, p1.x)); hix = fmaxf(hix, fmaxf(p0.x, p1.x));
    loy = fminf(loy, fminf(p0.y, p1.y)); hiy = fmaxf(hiy, fmaxf(p0.y, p1.y));
    loz = fminf(loz, fminf(p0.z, p1.z)); hiz = fmaxf(hiz, fmaxf(p0.z, p1.z));
    noi[2 * j]     = (((8191u - (unsigned)__builtin_bit_cast(int, p0.w)) << 13) | (unsigned)s0) + 1u;
    noi[2 * j + 1] = (((8191u - (unsigned)__builtin_bit_cast(int, p1.w)) << 13) | (unsigned)(s0 + 1)) + 1u;
  }
  unsigned bl0 = 0;
#pragma unroll
  for (int k = 0; k < PT; ++k) bl0 = (noi[k] > bl0) ? noi[k] : bl0;  // all dst equal
  unsigned long long bestpk =
      ((unsigned long long)(unsigned)__builtin_bit_cast(int, 1e10f) << 32) | bl0;

  float cx = cb[0], cy = cb[NPTS], cz = cb[2 * NPTS];
  int cur = 0;
  int parity = 0;
  for (int s = 0; s < NCTR; ++s) {
    if (t == 0) {
      cidx[b * NCTR + s] = cur;
      centers_out[(b * 3 + 0) * NCTR + s] = cx;
      centers_out[(b * 3 + 1) * NCTR + s] = cy;
      centers_out[(b * 3 + 2) * NCTR + s] = cz;
    }
    // bbox prune test
    float gx = fmaxf(fmaxf(lox - cx, cx - hix), 0.f);
    float gy = fmaxf(fmaxf(loy - cy, cy - hiy), 0.f);
    float gz = fmaxf(fmaxf(loz - cz, cz - hiz), 0.f);
    float d2m = gx * gx + gy * gy + gz * gz;
    float bval = __builtin_bit_cast(float, (unsigned)(bestpk >> 32));
    if (d2m * 0.9999f < bval) {
      f32x2 cx2 = {cx, cx}, cy2 = {cy, cy}, cz2 = {cz, cz};
      f32x2 bv2 = {-1.0f, -1.0f};
#pragma unroll
      for (int j = 0; j < P2; ++j) {
#pragma clang fp contract(off)
        // per-element ((dx*dx + dy*dy) + dz*dz), IEEE RN each op — numpy-exact
        f32x2 dx = px[j] - cx2;
        f32x2 dy = py[j] - cy2;
        f32x2 dz = pz[j] - cz2;
        f32x2 d2 = (dx * dx + dy * dy) + dz * dz;
        f32x2 nd = __builtin_elementwise_min(dst[j], d2);
        dst[j] = nd;
        bv2 = __builtin_elementwise_max(bv2, nd);
      }
      float bv = fmaxf(bv2.x, bv2.y);
      unsigned low = 0;
#pragma unroll
      for (int j = 0; j < P2; ++j) {
        if (dst[j].x == bv && noi[2 * j] > low) low = noi[2 * j];
        if (dst[j].y == bv && noi[2 * j + 1] > low) low = noi[2 * j + 1];
      }
      bestpk = ((unsigned long long)(unsigned)__builtin_bit_cast(int, bv) << 32) | low;
    }
    // wave reduce: f32 max, then u32 key max among candidates
    float bv = __builtin_bit_cast(float, (unsigned)(bestpk >> 32));
    float r = bv;
    r = dppmax<0x111>(r);
    r = dppmax<0x112>(r);
    r = dppmax<0x114>(r);
    r = dppmax<0x118>(r);
    r = dppmax<0x142>(r);
    r = dppmax<0x143>(r);
    float wm = __builtin_bit_cast(float,
        __builtin_amdgcn_readlane(__builtin_bit_cast(int, r), 63));
    unsigned cl = (bv == wm) ? (unsigned)bestpk : 0u;
    cl = dppumax<0x111>(cl);
    cl = dppumax<0x112>(cl);
    cl = dppumax<0x114>(cl);
    cl = dppumax<0x118>(cl);
    cl = dppumax<0x142>(cl);
    cl = dppumax<0x143>(cl);
    unsigned um = (unsigned)__builtin_amdgcn_readlane((int)cl, 63);
    if (lane == 0)
      red[parity][wid] =
          ((unsigned long long)(unsigned)__builtin_bit_cast(int, wm) << 32) | um;
    __syncthreads();
    unsigned long long best = red[parity][0];
#pragma unroll
    for (int k = 1; k < 4; ++k) {
      unsigned long long o = red[parity][k];
      best = (o > best) ? o : best;
    }
    unsigned low = (unsigned)best - 1u;
    int slot = (int)(low & 8191u);
    cur = 8191 - (int)(low >> 13);
    float4 cc = pts[slot];                     // single b128 LDS broadcast
    cx = cc.x; cy = cc.y; cz = cc.z;
    parity ^= 1;
  }
}

// ---------------- feat transpose to [B][N][64] bf16 ----------------
__global__ __launch_bounds__(256) void featT_kernel(const float* __restrict__ feat,
                                                    unsigned short* __restrict__ fT) {
  int b  = blockIdx.y;
  int j  = blockIdx.x * 64 + (threadIdx.x & 63);
  int cg = threadIdx.x >> 6;
  ushort8 v0, v1;
#pragma unroll
  for (int cc = 0; cc < 8; ++cc)
    v0[cc] = f2b(feat[((size_t)b * 64 + cg * 16 + cc) * NPTS + j]);
#pragma unroll
  for (int cc = 0; cc < 8; ++cc)
    v1[cc] = f2b(feat[((size_t)b * 64 + cg * 16 + 8 + cc) * NPTS + j]);
  unsigned short* dst = fT + ((size_t)b * NPTS + j) * 64 + cg * 16;
  *(ushort8*)dst = v0;
  *(ushort8*)(dst + 8) = v1;
}

// ---------------- ball query: wave per center, stream coords from L2 ----------------
__global__ __launch_bounds__(256) void bq_kernel(const float* __restrict__ coords,
                                                 const int* __restrict__ cidx,
                                                 int* __restrict__ nidx) {
  const int b = blockIdx.y;
  const int w = threadIdx.x >> 6, lane = threadIdx.x & 63;
  const int m = blockIdx.x * 4 + w;
  const float* cb = coords + (size_t)b * 3 * NPTS;
  const int cen = cidx[b * NCTR + m];
  const float cx = cb[cen], cy = cb[NPTS + cen], cz = cb[2 * NPTS + cen];
  int* outp = nidx + ((size_t)b * NCTR + m) * KNN;
  const float RR = (float)(0.2 * 0.2);   // exact f64->f32 like numpy
  int found = 0, first = -1;
  for (int chunk = 0; chunk < NPTS / 64 && found < KNN; ++chunk) {
    int p = chunk * 64 + lane;
    float dx = __fsub_rn(cx, cb[p]);
    float dy = __fsub_rn(cy, cb[NPTS + p]);
    float dz = __fsub_rn(cz, cb[2 * NPTS + p]);
    float d2 = __fadd_rn(__fadd_rn(__fmul_rn(dx, dx), __fmul_rn(dy, dy)), __fmul_rn(dz, dz));
    bool pred = d2 < RR;
    unsigned long long mask = __ballot(pred);
    if (pred) {
      int rank = __popcll(mask & ((1ull << lane) - 1ull));
      int slot = found + rank;
      if (slot < KNN) outp[slot] = p;
    }
    if (first < 0 && mask != 0ull) first = chunk * 64 + __builtin_ctzll(mask);
    found += __popcll(mask);
  }
  if (found < KNN) {
    int f = (first < 0) ? 0 : first;
    if (lane >= found) outp[lane] = f;
  }
}

// ---------------- fused conv chain ----------------
// NL=1: conv0 -> stats0.  NL=2: conv0->bn0->conv1 -> stats1 (+y1 if WRITEY1).
// NL=3: (READY1 ? y1 : conv0->bn0->conv1) -> bn1 -> conv2 -> per-group max/min + stats2.
template <int NL, bool READY1, bool WRITEY1>
__global__ __launch_bounds__(256) void fused_kernel(
    const unsigned short* __restrict__ fT, const float* __restrict__ coords,
    const int* __restrict__ cidx, const int* __restrict__ nidx,
    unsigned short* __restrict__ y1, const float* __restrict__ ss,
    const float* __restrict__ w0, const float* __restrict__ b0,
    const float* __restrict__ w1, const float* __restrict__ b1,
    const float* __restrict__ w2, const float* __restrict__ b2,
    float* __restrict__ psum, float* __restrict__ psqr,
    float* __restrict__ gmax, float* __restrict__ gmin) {
  __shared__ __align__(16) unsigned short Xs[4 * 64 * 128];   // 64 KB
  __shared__ __align__(16) unsigned short Wbuf[128 * 128];    // 32 KB
  __shared__ float s_bias[128];
  __shared__ float s_sc0[128], s_sh0[128], s_sc1[128], s_sh1[128];
  __shared__ float s_rs[4][128], s_rq[4][128];

  const int t = threadIdx.x;
  const int wg = t >> 6, lane = t & 63;
  const int r16 = lane & 15, kg = lane >> 4;
  const int g = blockIdx.x * 4 + wg;
  const int bb_ = g >> 10;
  const int rsw = lane & 7;
  unsigned short* xrow = &Xs[(wg * 64 + lane) * 128];

  if constexpr (NL >= 2 && !READY1) {
    if (t < 128) { s_sc0[t] = ss[t]; s_sh0[t] = ss[128 + t]; }
  }
  if constexpr (NL >= 3) {
    if (t < 128) { s_sc1[t] = ss[256 + t]; s_sh1[t] = ss[384 + t]; }
  }

  auto stageW = [&](const float* w, const float* bia, bool remap0, int oh) {
    for (int e = t; e < 128 * 128; e += 256) {
      int o = e >> 7, c = e & 127;
      float v;
      if (remap0) {
        int lc = (c < 64) ? (c + 3) : ((c < 67) ? (c - 64) : -1);
        v = (lc >= 0) ? w[o * 67 + lc] : 0.f;
      } else {
        v = w[((size_t)(oh * 128 + o)) * 128 + c];
      }
      Wbuf[(o << 7) + ((((c >> 3) ^ (o & 7)) << 3) | (c & 7))] = f2b(v);
    }
    if (t < 128) s_bias[t] = bia[oh * 128 + t];
  };

  auto statsOut = [&](float (&sv8)[8], float (&sq8)[8], int coff) {
#pragma unroll
    for (int nt = 0; nt < 8; ++nt) {
      sv8[nt] += __shfl_xor(sv8[nt], 16); sv8[nt] += __shfl_xor(sv8[nt], 32);
      sq8[nt] += __shfl_xor(sq8[nt], 16); sq8[nt] += __shfl_xor(sq8[nt], 32);
    }
    if (lane < 16) {
#pragma unroll
      for (int nt = 0; nt < 8; ++nt) {
        s_rs[wg][nt * 16 + lane] = sv8[nt];
        s_rq[wg][nt * 16 + lane] = sq8[nt];
      }
    }
    __syncthreads();
    if (t < 128) {
      float sB = s_rs[0][t] + s_rs[1][t] + s_rs[2][t] + s_rs[3][t];
      float qB = s_rq[0][t] + s_rq[1][t] + s_rq[2][t] + s_rq[3][t];
      psum[(size_t)blockIdx.x * 256 + coff + t] = sB;
      psqr[(size_t)blockIdx.x * 256 + coff + t] = qB;
    }
  };

  short8v a[4][4];

  if constexpr (!READY1) {
    {  // stage X0 (per-wave, lane = row)
      int j = nidx[(size_t)g * KNN + lane];
      int cen = cidx[g];
      const unsigned short* fr = fT + ((size_t)bb_ * NPTS + j) * 64;
#pragma unroll
      for (int ch = 0; ch < 8; ++ch)
        *(ushort8*)(xrow + ((ch ^ rsw) << 3)) = *(const ushort8*)(fr + ch * 8);
      const float* cb = coords + (size_t)bb_ * 3 * NPTS;
      float rx = __fsub_rn(cb[j], cb[cen]);
      float ry = __fsub_rn(cb[NPTS + j], cb[NPTS + cen]);
      float rz = __fsub_rn(cb[2 * NPTS + j], cb[2 * NPTS + cen]);
      ushort8 rv = {f2b(rx), f2b(ry), f2b(rz), 0, 0, 0, 0, 0};
      *(ushort8*)(xrow + ((8 ^ rsw) << 3)) = rv;
      ushort8 zz = {0, 0, 0, 0, 0, 0, 0, 0};
#pragma unroll
      for (int ch = 9; ch < 16; ++ch)
        *(ushort8*)(xrow + ((ch ^ rsw) << 3)) = zz;
    }
    stageW(w0, b0, true, 0);
    __syncthreads();

    // ---- layer 0 ----
#pragma unroll
    for (int st = 0; st < 4; ++st) {
      int row = st * 16 + r16;
#pragma unroll
      for (int ks = 0; ks < 3; ++ks)
        a[st][ks] = __builtin_bit_cast(short8v,
            *(const ushort8*)&Xs[(wg * 64 + row) * 128 + (((ks * 4 + kg) ^ (row & 7)) << 3)]);
    }
    {
      float sv8[8], sq8[8];
#pragma unroll
      for (int nt = 0; nt < 8; ++nt) { sv8[nt] = 0.f; sq8[nt] = 0.f; }
#pragma unroll
      for (int nt = 0; nt < 8; ++nt) {
        int o = nt * 16 + r16;
        short8v wb[3];
#pragma unroll
        for (int ks = 0; ks < 3; ++ks)
          wb[ks] = __builtin_bit_cast(short8v,
              *(const ushort8*)&Wbuf[(o << 7) + (((ks * 4 + kg) ^ (o & 7)) << 3)]);
        float bia = s_bias[o];
        float sc = 0.f, sh = 0.f;
        if constexpr (NL >= 2) { sc = s_sc0[o]; sh = s_sh0[o]; }
#pragma unroll
        for (int st = 0; st < 4; ++st) {
          f32x4 acc = {0.f, 0.f, 0.f, 0.f};
#pragma unroll
          for (int ks = 0; ks < 3; ++ks)
            acc = __builtin_amdgcn_mfma_f32_16x16x32_bf16(a[st][ks], wb[ks], acc, 0, 0, 0);
#pragma unroll
          for (int r = 0; r < 4; ++r) {
            float v = acc[r] + bia;
            if constexpr (NL == 1) {
              sv8[nt] += v; sq8[nt] = fmaf(v, v, sq8[nt]);
            } else {
              float x = fmaxf(fmaf(v, sc, sh), 0.f);
              int row = st * 16 + kg * 4 + r;
              Xs[(wg * 64 + row) * 128 + ((((o >> 3) ^ (row & 7)) << 3) | (o & 7))] = f2b(x);
            }
          }
        }
      }
      if constexpr (NL == 1) { statsOut(sv8, sq8, 0); return; }
    }

    // ---- layer 1 ----
    if constexpr (NL >= 2) {
      __syncthreads();
      stageW(w1, b1, false, 0);
      __syncthreads();
#pragma unroll
    for (int st = 0; st < 4; ++st) {
        int row = st * 16 + r16;
#pragma unroll
        for (int ks = 0; ks < 4; ++ks)
          a[st][ks] = __builtin_bit_cast(short8v,
              *(const ushort8*)&Xs[(wg * 64 + row) * 128 + (((ks * 4 + kg) ^ (row & 7)) << 3)]);
      }
      float sv8[8], sq8[8];
#pragma unroll
      for (int nt = 0; nt < 8; ++nt) { sv8[nt] = 0.f; sq8[nt] = 0.f; }
#pragma unroll
      for (int nt = 0; nt < 8; ++nt) {
        int o = nt * 16 + r16;
        short8v wb[4];
#pragma unroll
        for (int ks = 0; ks < 4; ++ks)
          wb[ks] = __builtin_bit_cast(short8v,
              *(const ushort8*)&Wbuf[(o << 7) + (((ks * 4 + kg) ^ (o & 7)) << 3)]);
        float bia = s_bias[o];
        float sc = 0.f, sh = 0.f;
        if constexpr (NL >= 3) { sc = s_sc1[o]; sh = s_sh1[o]; }
#pragma unroll
        for (int st = 0; st < 4; ++st) {
          f32x4 acc = {0.f, 0.f, 0.f, 0.f};
#pragma unroll
          for (int ks = 0; ks < 4; ++ks)
            acc = __builtin_amdgcn_mfma_f32_16x16x32_bf16(a[st][ks], wb[ks], acc, 0, 0, 0);
#pragma unroll
          for (int r = 0; r < 4; ++r) {
            float v = acc[r] + bia;
            int row = st * 16 + kg * 4 + r;
            if constexpr (NL == 2) {
              sv8[nt] += v; sq8[nt] = fmaf(v, v, sq8[nt]);
              if constexpr (WRITEY1)
                y1[((size_t)g * 64 + row) * 128 + o] = f2b(v);
            } else {
              float x = fmaxf(fmaf(v, sc, sh), 0.f);
              Xs[(wg * 64 + row) * 128 + ((((o >> 3) ^ (row & 7)) << 3) | (o & 7))] = f2b(x);
            }
          }
        }
      }
      if constexpr (NL == 2) { statsOut(sv8, sq8, 0); return; }
    }
  } else {
    // READY1 (NL==3): stage X2 = relu(bn1(y1)) per wave
    __syncthreads();   // s_sc1/s_sh1 ready
    const unsigned short* yr = y1 + ((size_t)g * 64 + lane) * 128;
#pragma unroll
    for (int ch = 0; ch < 16; ++ch) {
      ushort8 vv = *(const ushort8*)(yr + ch * 8);
      ushort8 ov;
#pragma unroll
      for (int jj = 0; jj < 8; ++jj) {
        int c = ch * 8 + jj;
        ov[jj] = f2b(fmaxf(fmaf(b2f(vv[jj]), s_sc1[c], s_sh1[c]), 0.f));
      }
      *(ushort8*)(xrow + ((ch ^ rsw) << 3)) = ov;
    }
  }

  // ---- layer 2 (NL==3): two output halves, max/min + stats ----
  if constexpr (NL == 3) {
#pragma unroll
    for (int st = 0; st < 4; ++st) {
      int row = st * 16 + r16;
#pragma unroll
      for (int ks = 0; ks < 4; ++ks)
        a[st][ks] = __builtin_bit_cast(short8v,
            *(const ushort8*)&Xs[(wg * 64 + row) * 128 + (((ks * 4 + kg) ^ (row & 7)) << 3)]);
    }
    for (int h = 0; h < 2; ++h) {
      __syncthreads();
      stageW(w2, b2, false, h);
      __syncthreads();
      float mx8[8], mn8[8], sv8[8], sq8[8];
#pragma unroll
      for (int nt = 0; nt < 8; ++nt) { mx8[nt] = -1e30f; mn8[nt] = 1e30f; sv8[nt] = 0.f; sq8[nt] = 0.f; }
#pragma unroll
      for (int nt = 0; nt < 8; ++nt) {
        int o = nt * 16 + r16;
        short8v wb[4];
#pragma unroll
        for (int ks = 0; ks < 4; ++ks)
          wb[ks] = __builtin_bit_cast(short8v,
              *(const ushort8*)&Wbuf[(o << 7) + (((ks * 4 + kg) ^ (o & 7)) << 3)]);
        float bia = s_bias[o];
#pragma unroll
        for (int st = 0; st < 4; ++st) {
          f32x4 acc = {0.f, 0.f, 0.f, 0.f};
#pragma unroll
          for (int ks = 0; ks < 4; ++ks)
            acc = __builtin_amdgcn_mfma_f32_16x16x32_bf16(a[st][ks], wb[ks], acc, 0, 0, 0);
#pragma unroll
          for (int r = 0; r < 4; ++r) {
            float v = acc[r] + bia;
            mx8[nt] = fmaxf(mx8[nt], v); mn8[nt] = fminf(mn8[nt], v);
            sv8[nt] += v; sq8[nt] = fmaf(v, v, sq8[nt]);
          }
        }
      }
#pragma unroll
      for (int nt = 0; nt < 8; ++nt) {
        mx8[nt] = fmaxf(mx8[nt], __shfl_xor(mx8[nt], 16));
        mx8[nt] = fmaxf(mx8[nt], __shfl_xor(mx8[nt], 32));
        mn8[nt] = fminf(mn8[nt], __shfl_xor(mn8[nt], 16));
        mn8[nt] = fminf(mn8[nt], __shfl_xor(mn8[nt], 32));
      }
      if (lane < 16) {
#pragma unroll
        for (int nt = 0; nt < 8; ++nt) {
          gmax[(size_t)g * 256 + h * 128 + nt * 16 + lane] = mx8[nt];
          gmin[(size_t)g * 256 + h * 128 + nt * 16 + lane] = mn8[nt];
        }
      }
      statsOut(sv8, sq8, h * 128);
    }
  }
}

// ---------------- stats finalize ----------------
template <int O>
__global__ __launch_bounds__(256) void ss_kernel(const float* __restrict__ psum,
                                                 const float* __restrict__ psqr,
                                                 const float* __restrict__ gamma,
                                                 const float* __restrict__ beta,
                                                 float* __restrict__ ss_out) {
  int c = blockIdx.x;
  int t = threadIdx.x;
  float s = 0.f, q = 0.f;
  for (int i = t; i < 2048; i += 256) {
    s += psum[(size_t)i * 256 + c];
    q += psqr[(size_t)i * 256 + c];
  }
  int lane = t & 63, wid = t >> 6;
#pragma unroll
  for (int off = 32; off > 0; off >>= 1) { s += __shfl_down(s, off); q += __shfl_down(q, off); }
  __shared__ float rv[4], rqv[4];
  if (lane == 0) { rv[wid] = s; rqv[wid] = q; }
  __syncthreads();
  if (t == 0) {
    s = rv[0] + rv[1] + rv[2] + rv[3];
    q = rqv[0] + rqv[1] + rqv[2] + rqv[3];
    const float inv = 1.0f / (float)SAMP;
    float mu = s * inv;
    float var = fmaxf(q * inv - mu * mu, 0.f);
    float rs = 1.0f / sqrtf(var + EPSB);
    float sc = gamma[c] * rs;
    ss_out[c] = sc;
    ss_out[O + c] = beta[c] - mu * sc;
  }
}

// ---------------- final: out = relu(max(sc*mx+sh, sc*mn+sh)), LDS transpose ----------------
__global__ __launch_bounds__(256) void final_kernel(const float* __restrict__ gmax,
                                                    const float* __restrict__ gmin,
                                                    const float* __restrict__ ss2,
                                                    float* __restrict__ out) {
  int b = blockIdx.x >> 5, mt = blockIdx.x & 31;
  int t = threadIdx.x;
  __shared__ float tile[32][257];
  float sc = ss2[t], sh = ss2[256 + t];
  size_t base = ((size_t)b * 1024 + mt * 32) * 256;
#pragma unroll
  for (int r = 0; r < 32; ++r) {
    float A = fmaf(gmax[base + r * 256 + t], sc, sh);
    float C = fmaf(gmin[base + r * 256 + t], sc, sh);
    tile[r][t] = fmaxf(fmaxf(A, C), 0.f);
  }
  __syncthreads();
  for (int i = t; i < 8192; i += 256) {
    int o = i >> 5, ml = i & 31;
    out[((size_t)b * 256 + o) * 1024 + mt * 32 + ml] = tile[ml][o];
  }
}

__global__ void cond_kernel(const float* __restrict__ cond, float* __restrict__ dst) {
  dst[threadIdx.x] = cond[threadIdx.x];
}

extern "C" void kernel_launch(void* const* d_in, const int* in_sizes, int n_in,
                              void* d_out, int out_size, void* d_ws, size_t ws_size,
                              hipStream_t stream) {
  const float* feat   = (const float*)d_in[0];
  const float* coords = (const float*)d_in[1];
  const float* cond   = (const float*)d_in[2];
  const float* w0  = (const float*)d_in[3];
  const float* b0  = (const float*)d_in[4];
  const float* ga0 = (const float*)d_in[5];
  const float* be0 = (const float*)d_in[6];
  const float* w1  = (const float*)d_in[7];
  const float* b1  = (const float*)d_in[8];
  const float* ga1 = (const float*)d_in[9];
  const float* be1 = (const float*)d_in[10];
  const float* w2  = (const float*)d_in[11];
  const float* b2  = (const float*)d_in[12];
  const float* ga2 = (const float*)d_in[13];
  const float* be2 = (const float*)d_in[14];

  char* ws = (char*)d_ws;
  int* cidxp = (int*)(ws + OFF_CIDX);
  int* nidxp = (int*)(ws + OFF_NIDX);
  float* ss   = (float*)(ws + OFF_SS);
  float* psum = (float*)(ws + OFF_PSUM);
  float* psqr = (float*)(ws + OFF_PSQR);
  float* gmax = (float*)(ws + OFF_GMAX);
  float* gmin = (float*)(ws + OFF_GMIN);
  unsigned short* fT = (unsigned short*)(ws + OFF_FT);
  unsigned short* y1 = (unsigned short*)(ws + OFF_Y1);

  float* out         = (float*)d_out;
  float* centers_out = out + (size_t)8 * 256 * 1024;
  float* cond_out    = centers_out + (size_t)8 * 3 * 1024;

  const bool big = (ws_size >= NEED_BIG);

  fps_kernel<<<8, 256, 0, stream>>>(coords, cidxp, centers_out);
  featT_kernel<<<dim3(128, 8), 256, 0, stream>>>(feat, fT);
  bq_kernel<<<dim3(256, 8), 256, 0, stream>>>(coords, cidxp, nidxp);

  fused_kernel<1, false, false><<<2048, 256, 0, stream>>>(
      fT, coords, cidxp, nidxp, y1, ss, w0, b0, w1, b1, w2, b2, psum, psqr, gmax, gmin);
  ss_kernel<128><<<128, 256, 0, stream>>>(psum, psqr, ga0, be0, ss);

  if (big) {
    fused_kernel<2, false, true><<<2048, 256, 0, stream>>>(
        fT, coords, cidxp, nidxp, y1, ss, w0, b0, w1, b1, w2, b2, psum, psqr, gmax, gmin);
  } else {
    fused_kernel<2, false, false><<<2048, 256, 0, stream>>>(
        fT, coords, cidxp, nidxp, y1, ss, w0, b0, w1, b1, w2, b2, psum, psqr, gmax, gmin);
  }
  ss_kernel<128><<<128, 256, 0, stream>>>(psum, psqr, ga1, be1, ss + 256);

  if (big) {
    fused_kernel<3, true, false><<<2048, 256, 0, stream>>>(
        fT, coords, cidxp, nidxp, y1, ss, w0, b0, w1, b1, w2, b2, psum, psqr, gmax, gmin);
  } else {
    fused_kernel<3, false, false><<<2048, 256, 0, stream>>>(
        fT, coords, cidxp, nidxp, y1, ss, w0, b0, w1, b1, w2, b2, psum, psqr, gmax, gmin);
  }
  ss_kernel<256><<<256, 256, 0, stream>>>(psum, psqr, ga2, be2, ss + 512);

  final_kernel<<<256, 256, 0, stream>>>(gmax, gmin, ss + 512, out);
  cond_kernel<<<1, 512, 0, stream>>>(cond, cond_out);
}

// Round 8
// 1319.870 us; speedup vs baseline: 1.4944x; 1.4944x over previous
//
#include <hip/hip_runtime.h>

#define NB    8
#define NPTS  8192
#define NCTR  1024
#define KNN   64
#define NGRP  8192
#define SAMP  524288
#define EPSB  1e-5f

// ---- ws layout (bytes), total SMALL = ~31.5 MB, BIG = ~166 MB ----
#define OFF_CIDX 0ull
#define OFF_NIDX 32768ull
#define OFF_SS   2129920ull
#define OFF_PSUM 2134016ull
#define OFF_PSQR 4231168ull
#define OFF_GMAX 6328320ull
#define OFF_GMIN 14716928ull
#define OFF_FT   23105536ull
#define OFF_Y1   31494144ull
#define NEED_BIG 165711872ull

typedef unsigned short ushort8 __attribute__((ext_vector_type(8)));
typedef short short8v __attribute__((ext_vector_type(8)));
typedef float f32x4 __attribute__((ext_vector_type(4)));

__device__ __forceinline__ unsigned short f2b(float f) {
  unsigned int u = __builtin_bit_cast(unsigned int, f);
  u += 0x7fffu + ((u >> 16) & 1u);
  return (unsigned short)(u >> 16);
}
__device__ __forceinline__ float b2f(unsigned short s) {
  unsigned int u = ((unsigned int)s) << 16;
  return __builtin_bit_cast(float, u);
}

// DPP-assisted max step: r = max(r, dpp_move(r)) ; bound_ctrl=1 -> invalid src reads 0.0
// (identity for non-negative distances).
template <int CTRL>
__device__ __forceinline__ float dppmax(float x) {
  int m = __builtin_amdgcn_update_dpp(0, __builtin_bit_cast(int, x), CTRL, 0xf, 0xf, true);
  return fmaxf(x, __builtin_bit_cast(float, m));
}

// ---------------- FPS (R5 version): 4 waves, DPP wave-max + ballot argmax ----------------
// Thread t owns contiguous points [t*32, t*32+32) -> lane order == index order, so
// ballot+ctz after the max reduce picks the smallest index (numpy first-occurrence).
// Inter-wave: u64 pack (bits(dist)<<32)|~idx; max == (max dist, then min idx).
__global__ __launch_bounds__(256) void fps_kernel(const float* __restrict__ coords,
                                                  int* __restrict__ cidx,
                                                  float* __restrict__ centers_out) {
  const int b = blockIdx.x;
  const int t = threadIdx.x;
  const int wid = t >> 6, lane = t & 63;
  __shared__ float4 sc4[NPTS];                 // 128 KB packed coords
  __shared__ unsigned long long red[2][4];
  const float* cb = coords + (size_t)b * 3 * NPTS;
  for (int i = t; i < NPTS; i += 256)
    sc4[i] = make_float4(cb[i], cb[NPTS + i], cb[2 * NPTS + i], 0.f);
  __syncthreads();
  constexpr int PT = NPTS / 256;  // 32, contiguous per thread
  float px[PT], py[PT], pz[PT], dst[PT];
#pragma unroll
  for (int i = 0; i < PT; ++i) {
    int p = t * PT + i;
    px[i] = cb[p]; py[i] = cb[NPTS + p]; pz[i] = cb[2 * NPTS + p];
    dst[i] = 1e10f;
  }
  int cur = 0;
  float4 c0 = sc4[0];
  float cx = c0.x, cy = c0.y, cz = c0.z;
  int parity = 0;
  for (int s = 0; s < NCTR; ++s) {
    if (t == 0) {
      cidx[b * NCTR + s] = cur;
      centers_out[(b * 3 + 0) * NCTR + s] = cx;
      centers_out[(b * 3 + 1) * NCTR + s] = cy;
      centers_out[(b * 3 + 2) * NCTR + s] = cz;
    }
    float bv = -1.0f; int bi = 0;
#pragma unroll
    for (int i = 0; i < PT; ++i) {
      // exact numpy f32 order: ((dx*dx + dy*dy) + dz*dz), no fma contraction
      float dx = __fsub_rn(px[i], cx);
      float dy = __fsub_rn(py[i], cy);
      float dz = __fsub_rn(pz[i], cz);
      float d2 = __fadd_rn(__fadd_rn(__fmul_rn(dx, dx), __fmul_rn(dy, dy)), __fmul_rn(dz, dz));
      float nd = fminf(dst[i], d2);
      dst[i] = nd;
      if (nd > bv) { bv = nd; bi = t * PT + i; }   // ascending i -> first occurrence
    }
    // in-wave max via DPP: row_shr 1/2/4/8 then row_bcast15/31; lane 63 holds wave max
    float r = bv;
    r = dppmax<0x111>(r);
    r = dppmax<0x112>(r);
    r = dppmax<0x114>(r);
    r = dppmax<0x118>(r);
    r = dppmax<0x142>(r);
    r = dppmax<0x143>(r);
    float wm = __builtin_bit_cast(float,
        __builtin_amdgcn_readlane(__builtin_bit_cast(int, r), 63));
    unsigned long long mask = __ballot(bv == wm);
    int widx = __shfl(bi, (int)__builtin_ctzll(mask));  // lowest lane == smallest index
    if (lane == 0)
      red[parity][wid] =
          ((unsigned long long)__builtin_bit_cast(unsigned int, wm) << 32) |
          (unsigned long long)(~(unsigned int)widx);
    __syncthreads();
    unsigned long long best = red[parity][0];
#pragma unroll
    for (int k = 1; k < 4; ++k) {
      unsigned long long o = red[parity][k];
      best = (o > best) ? o : best;
    }
    cur = (int)(~(unsigned int)best);
    float4 cc = sc4[cur];                       // single b128 LDS broadcast
    cx = cc.x; cy = cc.y; cz = cc.z;
    parity ^= 1;
  }
}

// ---------------- feat transpose to [B][N][64] bf16 ----------------
__global__ __launch_bounds__(256) void featT_kernel(const float* __restrict__ feat,
                                                    unsigned short* __restrict__ fT) {
  int b  = blockIdx.y;
  int j  = blockIdx.x * 64 + (threadIdx.x & 63);
  int cg = threadIdx.x >> 6;
  ushort8 v0, v1;
#pragma unroll
  for (int cc = 0; cc < 8; ++cc)
    v0[cc] = f2b(feat[((size_t)b * 64 + cg * 16 + cc) * NPTS + j]);
#pragma unroll
  for (int cc = 0; cc < 8; ++cc)
    v1[cc] = f2b(feat[((size_t)b * 64 + cg * 16 + 8 + cc) * NPTS + j]);
  unsigned short* dst = fT + ((size_t)b * NPTS + j) * 64 + cg * 16;
  *(ushort8*)dst = v0;
  *(ushort8*)(dst + 8) = v1;
}

// ---------------- ball query: wave per center, stream coords from L2 ----------------
__global__ __launch_bounds__(256) void bq_kernel(const float* __restrict__ coords,
                                                 const int* __restrict__ cidx,
                                                 int* __restrict__ nidx) {
  const int b = blockIdx.y;
  const int w = threadIdx.x >> 6, lane = threadIdx.x & 63;
  const int m = blockIdx.x * 4 + w;
  const float* cb = coords + (size_t)b * 3 * NPTS;
  const int cen = cidx[b * NCTR + m];
  const float cx = cb[cen], cy = cb[NPTS + cen], cz = cb[2 * NPTS + cen];
  int* outp = nidx + ((size_t)b * NCTR + m) * KNN;
  const float RR = (float)(0.2 * 0.2);   // exact f64->f32 like numpy
  int found = 0, first = -1;
  for (int chunk = 0; chunk < NPTS / 64 && found < KNN; ++chunk) {
    int p = chunk * 64 + lane;
    float dx = __fsub_rn(cx, cb[p]);
    float dy = __fsub_rn(cy, cb[NPTS + p]);
    float dz = __fsub_rn(cz, cb[2 * NPTS + p]);
    float d2 = __fadd_rn(__fadd_rn(__fmul_rn(dx, dx), __fmul_rn(dy, dy)), __fmul_rn(dz, dz));
    bool pred = d2 < RR;
    unsigned long long mask = __ballot(pred);
    if (pred) {
      int rank = __popcll(mask & ((1ull << lane) - 1ull));
      int slot = found + rank;
      if (slot < KNN) outp[slot] = p;
    }
    if (first < 0 && mask != 0ull) first = chunk * 64 + __builtin_ctzll(mask);
    found += __popcll(mask);
  }
  if (found < KNN) {
    int f = (first < 0) ? 0 : first;
    if (lane >= found) outp[lane] = f;
  }
}

// ---------------- fused conv chain: 512 thr, 8 waves, 2 waves per group ----------------
// Wave wv = group*2 + hp; the pair shares one group's X tile; each wave computes
// output channels o in [hp*64, hp*64+64) (nt split). 2 waves/SIMD hide staging latency.
// NL=1: conv0 -> stats0.  NL=2: conv0->bn0->conv1 -> stats1 (+y1 if WRITEY1).
// NL=3: (READY1 ? y1 : conv0->bn0->conv1) -> bn1 -> conv2 -> per-group max/min + stats2.
template <int NL, bool READY1, bool WRITEY1>
__global__ __launch_bounds__(512) void fused_kernel(
    const unsigned short* __restrict__ fT, const float* __restrict__ coords,
    const int* __restrict__ cidx, const int* __restrict__ nidx,
    unsigned short* __restrict__ y1, const float* __restrict__ ss,
    const float* __restrict__ w0, const float* __restrict__ b0,
    const float* __restrict__ w1, const float* __restrict__ b1,
    const float* __restrict__ w2, const float* __restrict__ b2,
    float* __restrict__ psum, float* __restrict__ psqr,
    float* __restrict__ gmax, float* __restrict__ gmin) {
  __shared__ __align__(16) unsigned short Xs[4 * 64 * 128];   // 64 KB
  __shared__ __align__(16) unsigned short Wbuf[128 * 128];    // 32 KB
  __shared__ float s_bias[128];
  __shared__ float s_sc0[128], s_sh0[128], s_sc1[128], s_sh1[128];
  __shared__ float s_rs[8][64], s_rq[8][64];

  const int t = threadIdx.x;
  const int wv = t >> 6, lane = t & 63;
  const int wg = wv >> 1;          // group 0..3
  const int hp = wv & 1;           // output-half parity
  const int r16 = lane & 15, kg = lane >> 4;
  const int g = blockIdx.x * 4 + wg;
  const int bb_ = g >> 10;
  const int rsw = lane & 7;
  unsigned short* xrow = &Xs[(wg * 64 + lane) * 128];

  if constexpr (NL >= 2 && !READY1) {
    if (t < 128) { s_sc0[t] = ss[t]; s_sh0[t] = ss[128 + t]; }
  }
  if constexpr (NL >= 3) {
    if (t < 128) { s_sc1[t] = ss[256 + t]; s_sh1[t] = ss[384 + t]; }
  }

  auto stageW = [&](const float* w, const float* bia, bool remap0, int oh) {
    for (int e = t; e < 128 * 128; e += 512) {
      int o = e >> 7, c = e & 127;
      float v;
      if (remap0) {
        int lc = (c < 64) ? (c + 3) : ((c < 67) ? (c - 64) : -1);
        v = (lc >= 0) ? w[o * 67 + lc] : 0.f;
      } else {
        v = w[((size_t)(oh * 128 + o)) * 128 + c];
      }
      Wbuf[(o << 7) + ((((c >> 3) ^ (o & 7)) << 3) | (c & 7))] = f2b(v);
    }
    if (t < 128) s_bias[t] = bia[oh * 128 + t];
  };

  // per-wave partials over its 4 nt tiles (channels hp*64 + k*16 + r16)
  auto statsOut = [&](float (&sv4)[4], float (&sq4)[4], int coff) {
#pragma unroll
    for (int k = 0; k < 4; ++k) {
      sv4[k] += __shfl_xor(sv4[k], 16); sv4[k] += __shfl_xor(sv4[k], 32);
      sq4[k] += __shfl_xor(sq4[k], 16); sq4[k] += __shfl_xor(sq4[k], 32);
    }
    if (lane < 16) {
#pragma unroll
      for (int k = 0; k < 4; ++k) {
        s_rs[wv][k * 16 + lane] = sv4[k];
        s_rq[wv][k * 16 + lane] = sq4[k];
      }
    }
    __syncthreads();
    if (t < 128) {
      int hp2 = t >> 6, cl = t & 63;
      float sB = s_rs[0 + hp2][cl] + s_rs[2 + hp2][cl] + s_rs[4 + hp2][cl] + s_rs[6 + hp2][cl];
      float qB = s_rq[0 + hp2][cl] + s_rq[2 + hp2][cl] + s_rq[4 + hp2][cl] + s_rq[6 + hp2][cl];
      psum[(size_t)blockIdx.x * 256 + coff + t] = sB;
      psqr[(size_t)blockIdx.x * 256 + coff + t] = qB;
    }
  };

  short8v a[4][4];

  if constexpr (!READY1) {
    if (hp == 0) {  // even wave stages its group's X0 (lane = row)
      int j = nidx[(size_t)g * KNN + lane];
      int cen = cidx[g];
      const unsigned short* fr = fT + ((size_t)bb_ * NPTS + j) * 64;
#pragma unroll
      for (int ch = 0; ch < 8; ++ch)
        *(ushort8*)(xrow + ((ch ^ rsw) << 3)) = *(const ushort8*)(fr + ch * 8);
      const float* cb = coords + (size_t)bb_ * 3 * NPTS;
      float rx = __fsub_rn(cb[j], cb[cen]);
      float ry = __fsub_rn(cb[NPTS + j], cb[NPTS + cen]);
      float rz = __fsub_rn(cb[2 * NPTS + j], cb[2 * NPTS + cen]);
      ushort8 rv = {f2b(rx), f2b(ry), f2b(rz), 0, 0, 0, 0, 0};
      *(ushort8*)(xrow + ((8 ^ rsw) << 3)) = rv;
      ushort8 zz = {0, 0, 0, 0, 0, 0, 0, 0};
#pragma unroll
      for (int ch = 9; ch < 16; ++ch)
        *(ushort8*)(xrow + ((ch ^ rsw) << 3)) = zz;
    }
    stageW(w0, b0, true, 0);
    __syncthreads();

    // ---- layer 0 ----
#pragma unroll
    for (int st = 0; st < 4; ++st) {
      int row = st * 16 + r16;
#pragma unroll
      for (int ks = 0; ks < 3; ++ks)
        a[st][ks] = __builtin_bit_cast(short8v,
            *(const ushort8*)&Xs[(wg * 64 + row) * 128 + (((ks * 4 + kg) ^ (row & 7)) << 3)]);
    }
    {
      float sv4[4], sq4[4];
#pragma unroll
      for (int k = 0; k < 4; ++k) { sv4[k] = 0.f; sq4[k] = 0.f; }
#pragma unroll
      for (int k = 0; k < 4; ++k) {
        int o = hp * 64 + k * 16 + r16;
        short8v wb[3];
#pragma unroll
        for (int ks = 0; ks < 3; ++ks)
          wb[ks] = __builtin_bit_cast(short8v,
              *(const ushort8*)&Wbuf[(o << 7) + (((ks * 4 + kg) ^ (o & 7)) << 3)]);
        float bia = s_bias[o];
        float sc = 0.f, sh = 0.f;
        if constexpr (NL >= 2) { sc = s_sc0[o]; sh = s_sh0[o]; }
#pragma unroll
        for (int st = 0; st < 4; ++st) {
          f32x4 acc = {0.f, 0.f, 0.f, 0.f};
#pragma unroll
          for (int ks = 0; ks < 3; ++ks)
            acc = __builtin_amdgcn_mfma_f32_16x16x32_bf16(a[st][ks], wb[ks], acc, 0, 0, 0);
#pragma unroll
          for (int r = 0; r < 4; ++r) {
            float v = acc[r] + bia;
            if constexpr (NL == 1) {
              sv4[k] += v; sq4[k] = fmaf(v, v, sq4[k]);
            } else {
              float x = fmaxf(fmaf(v, sc, sh), 0.f);
              int row = st * 16 + kg * 4 + r;
              Xs[(wg * 64 + row) * 128 + ((((o >> 3) ^ (row & 7)) << 3) | (o & 7))] = f2b(x);
            }
          }
        }
      }
      if constexpr (NL == 1) { statsOut(sv4, sq4, 0); return; }
    }

    // ---- layer 1 ----
    if constexpr (NL >= 2) {
      __syncthreads();
      stageW(w1, b1, false, 0);
      __syncthreads();
#pragma unroll
      for (int st = 0; st < 4; ++st) {
        int row = st * 16 + r16;
#pragma unroll
        for (int ks = 0; ks < 4; ++ks)
          a[st][ks] = __builtin_bit_cast(short8v,
              *(const ushort8*)&Xs[(wg * 64 + row) * 128 + (((ks * 4 + kg) ^ (row & 7)) << 3)]);
      }
      float sv4[4], sq4[4];
#pragma unroll
      for (int k = 0; k < 4; ++k) { sv4[k] = 0.f; sq4[k] = 0.f; }
#pragma unroll
      for (int k = 0; k < 4; ++k) {
        int o = hp * 64 + k * 16 + r16;
        short8v wb[4];
#pragma unroll
        for (int ks = 0; ks < 4; ++ks)
          wb[ks] = __builtin_bit_cast(short8v,
              *(const ushort8*)&Wbuf[(o << 7) + (((ks * 4 + kg) ^ (o & 7)) << 3)]);
        float bia = s_bias[o];
        float sc = 0.f, sh = 0.f;
        if constexpr (NL >= 3) { sc = s_sc1[o]; sh = s_sh1[o]; }
#pragma unroll
        for (int st = 0; st < 4; ++st) {
          f32x4 acc = {0.f, 0.f, 0.f, 0.f};
#pragma unroll
          for (int ks = 0; ks < 4; ++ks)
            acc = __builtin_amdgcn_mfma_f32_16x16x32_bf16(a[st][ks], wb[ks], acc, 0, 0, 0);
#pragma unroll
          for (int r = 0; r < 4; ++r) {
            float v = acc[r] + bia;
            int row = st * 16 + kg * 4 + r;
            if constexpr (NL == 2) {
              sv4[k] += v; sq4[k] = fmaf(v, v, sq4[k]);
              if constexpr (WRITEY1)
                y1[((size_t)g * 64 + row) * 128 + o] = f2b(v);
            } else {
              float x = fmaxf(fmaf(v, sc, sh), 0.f);
              Xs[(wg * 64 + row) * 128 + ((((o >> 3) ^ (row & 7)) << 3) | (o & 7))] = f2b(x);
            }
          }
        }
      }
      if constexpr (NL == 2) { statsOut(sv4, sq4, 0); return; }
    }
  } else {
    // READY1 (NL==3): even wave stages X2 = relu(bn1(y1)) for its group
    __syncthreads();   // s_sc1/s_sh1 ready
    if (hp == 0) {
      const unsigned short* yr = y1 + ((size_t)g * 64 + lane) * 128;
#pragma unroll
      for (int ch = 0; ch < 16; ++ch) {
        ushort8 vv = *(const ushort8*)(yr + ch * 8);
        ushort8 ov;
#pragma unroll
        for (int jj = 0; jj < 8; ++jj) {
          int c = ch * 8 + jj;
          ov[jj] = f2b(fmaxf(fmaf(b2f(vv[jj]), s_sc1[c], s_sh1[c]), 0.f));
        }
        *(ushort8*)(xrow + ((ch ^ rsw) << 3)) = ov;
      }
    }
  }

  // ---- layer 2 (NL==3): two output halves, max/min + stats ----
  if constexpr (NL == 3) {
    __syncthreads();   // X2 tile complete (cross-wave: staged/stored by pair partner)
#pragma unroll
    for (int st = 0; st < 4; ++st) {
      int row = st * 16 + r16;
#pragma unroll
      for (int ks = 0; ks < 4; ++ks)
        a[st][ks] = __builtin_bit_cast(short8v,
            *(const ushort8*)&Xs[(wg * 64 + row) * 128 + (((ks * 4 + kg) ^ (row & 7)) << 3)]);
    }
    for (int h = 0; h < 2; ++h) {
      __syncthreads();
      stageW(w2, b2, false, h);
      __syncthreads();
      float mx4[4], mn4[4], sv4[4], sq4[4];
#pragma unroll
      for (int k = 0; k < 4; ++k) { mx4[k] = -1e30f; mn4[k] = 1e30f; sv4[k] = 0.f; sq4[k] = 0.f; }
#pragma unroll
      for (int k = 0; k < 4; ++k) {
        int o = hp * 64 + k * 16 + r16;
        short8v wb[4];
#pragma unroll
        for (int ks = 0; ks < 4; ++ks)
          wb[ks] = __builtin_bit_cast(short8v,
              *(const ushort8*)&Wbuf[(o << 7) + (((ks * 4 + kg) ^ (o & 7)) << 3)]);
        float bia = s_bias[o];
#pragma unroll
        for (int st = 0; st < 4; ++st) {
          f32x4 acc = {0.f, 0.f, 0.f, 0.f};
#pragma unroll
          for (int ks = 0; ks < 4; ++ks)
            acc = __builtin_amdgcn_mfma_f32_16x16x32_bf16(a[st][ks], wb[ks], acc, 0, 0, 0);
#pragma unroll
          for (int r = 0; r < 4; ++r) {
            float v = acc[r] + bia;
            mx4[k] = fmaxf(mx4[k], v); mn4[k] = fminf(mn4[k], v);
            sv4[k] += v; sq4[k] = fmaf(v, v, sq4[k]);
          }
        }
      }
#pragma unroll
      for (int k = 0; k < 4; ++k) {
        mx4[k] = fmaxf(mx4[k], __shfl_xor(mx4[k], 16));
        mx4[k] = fmaxf(mx4[k], __shfl_xor(mx4[k], 32));
        mn4[k] = fminf(mn4[k], __shfl_xor(mn4[k], 16));
        mn4[k] = fminf(mn4[k], __shfl_xor(mn4[k], 32));
      }
      if (lane < 16) {
#pragma unroll
        for (int k = 0; k < 4; ++k) {
          gmax[(size_t)g * 256 + h * 128 + hp * 64 + k * 16 + lane] = mx4[k];
          gmin[(size_t)g * 256 + h * 128 + hp * 64 + k * 16 + lane] = mn4[k];
        }
      }
      statsOut(sv4, sq4, h * 128);
    }
  }
}

// ---------------- stats finalize ----------------
template <int O>
__global__ __launch_bounds__(256) void ss_kernel(const float* __restrict__ psum,
                                                 const float* __restrict__ psqr,
                                                 const float* __restrict__ gamma,
                                                 const float* __restrict__ beta,
                                                 float* __restrict__ ss_out) {
  int c = blockIdx.x;
  int t = threadIdx.x;
  float s = 0.f, q = 0.f;
  for (int i = t; i < 2048; i += 256) {
    s += psum[(size_t)i * 256 + c];
    q += psqr[(size_t)i * 256 + c];
  }
  int lane = t & 63, wid = t >> 6;
#pragma unroll
  for (int off = 32; off > 0; off >>= 1) { s += __shfl_down(s, off); q += __shfl_down(q, off); }
  __shared__ float rv[4], rqv[4];
  if (lane == 0) { rv[wid] = s; rqv[wid] = q; }
  __syncthreads();
  if (t == 0) {
    s = rv[0] + rv[1] + rv[2] + rv[3];
    q = rqv[0] + rqv[1] + rqv[2] + rqv[3];
    const float inv = 1.0f / (float)SAMP;
    float mu = s * inv;
    float var = fmaxf(q * inv - mu * mu, 0.f);
    float rs = 1.0f / sqrtf(var + EPSB);
    float sc = gamma[c] * rs;
    ss_out[c] = sc;
    ss_out[O + c] = beta[c] - mu * sc;
  }
}

// ---------------- final: out = relu(max(sc*mx+sh, sc*mn+sh)), LDS transpose ----------------
__global__ __launch_bounds__(256) void final_kernel(const float* __restrict__ gmax,
                                                    const float* __restrict__ gmin,
                                                    const float* __restrict__ ss2,
                                                    float* __restrict__ out) {
  int b = blockIdx.x >> 5, mt = blockIdx.x & 31;
  int t = threadIdx.x;
  __shared__ float tile[32][257];
  float sc = ss2[t], sh = ss2[256 + t];
  size_t base = ((size_t)b * 1024 + mt * 32) * 256;
#pragma unroll
  for (int r = 0; r < 32; ++r) {
    float A = fmaf(gmax[base + r * 256 + t], sc, sh);
    float C = fmaf(gmin[base + r * 256 + t], sc, sh);
    tile[r][t] = fmaxf(fmaxf(A, C), 0.f);
  }
  __syncthreads();
  for (int i = t; i < 8192; i += 256) {
    int o = i >> 5, ml = i & 31;
    out[((size_t)b * 256 + o) * 1024 + mt * 32 + ml] = tile[ml][o];
  }
}

__global__ void cond_kernel(const float* __restrict__ cond, float* __restrict__ dst) {
  dst[threadIdx.x] = cond[threadIdx.x];
}

extern "C" void kernel_launch(void* const* d_in, const int* in_sizes, int n_in,
                              void* d_out, int out_size, void* d_ws, size_t ws_size,
                              hipStream_t stream) {
  const float* feat   = (const float*)d_in[0];
  const float* coords = (const float*)d_in[1];
  const float* cond   = (const float*)d_in[2];
  const float* w0  = (const float*)d_in[3];
  const float* b0  = (const float*)d_in[4];
  const float* ga0 = (const float*)d_in[5];
  const float* be0 = (const float*)d_in[6];
  const float* w1  = (const float*)d_in[7];
  const float* b1  = (const float*)d_in[8];
  const float* ga1 = (const float*)d_in[9];
  const float* be1 = (const float*)d_in[10];
  const float* w2  = (const float*)d_in[11];
  const float* b2  = (const float*)d_in[12];
  const float* ga2 = (const float*)d_in[13];
  const float* be2 = (const float*)d_in[14];

  char* ws = (char*)d_ws;
  int* cidxp = (int*)(ws + OFF_CIDX);
  int* nidxp = (int*)(ws + OFF_NIDX);
  float* ss   = (float*)(ws + OFF_SS);
  float* psum = (float*)(ws + OFF_PSUM);
  float* psqr = (float*)(ws + OFF_PSQR);
  float* gmax = (float*)(ws + OFF_GMAX);
  float* gmin = (float*)(ws + OFF_GMIN);
  unsigned short* fT = (unsigned short*)(ws + OFF_FT);
  unsigned short* y1 = (unsigned short*)(ws + OFF_Y1);

  float* out         = (float*)d_out;
  float* centers_out = out + (size_t)8 * 256 * 1024;
  float* cond_out    = centers_out + (size_t)8 * 3 * 1024;

  const bool big = (ws_size >= NEED_BIG);

  fps_kernel<<<8, 256, 0, stream>>>(coords, cidxp, centers_out);
  featT_kernel<<<dim3(128, 8), 256, 0, stream>>>(feat, fT);
  bq_kernel<<<dim3(256, 8), 256, 0, stream>>>(coords, cidxp, nidxp);

  fused_kernel<1, false, false><<<2048, 512, 0, stream>>>(
      fT, coords, cidxp, nidxp, y1, ss, w0, b0, w1, b1, w2, b2, psum, psqr, gmax, gmin);
  ss_kernel<128><<<128, 256, 0, stream>>>(psum, psqr, ga0, be0, ss);

  if (big) {
    fused_kernel<2, false, true><<<2048, 512, 0, stream>>>(
        fT, coords, cidxp, nidxp, y1, ss, w0, b0, w1, b1, w2, b2, psum, psqr, gmax, gmin);
  } else {
    fused_kernel<2, false, false><<<2048, 512, 0, stream>>>(
        fT, coords, cidxp, nidxp, y1, ss, w0, b0, w1, b1, w2, b2, psum, psqr, gmax, gmin);
  }
  ss_kernel<128><<<128, 256, 0, stream>>>(psum, psqr, ga1, be1, ss + 256);

  if (big) {
    fused_kernel<3, true, false><<<2048, 512, 0, stream>>>(
        fT, coords, cidxp, nidxp, y1, ss, w0, b0, w1, b1, w2, b2, psum, psqr, gmax, gmin);
  } else {
    fused_kernel<3, false, false><<<2048, 512, 0, stream>>>(
        fT, coords, cidxp, nidxp, y1, ss, w0, b0, w1, b1, w2, b2, psum, psqr, gmax, gmin);
  }
  ss_kernel<256><<<256, 256, 0, stream>>>(psum, psqr, ga2, be2, ss + 512);

  final_kernel<<<256, 256, 0, stream>>>(gmax, gmin, ss + 512, out);
  cond_kernel<<<1, 512, 0, stream>>>(cond, cond_out);
}